// Round 1
// baseline (200.672 us; speedup 1.0000x reference)
//
#include <hip/hip_runtime.h>
#include <hip/hip_bf16.h>

#define NB 16
#define SEQ 2048
#define EDIM 256

typedef __attribute__((ext_vector_type(16))) float f32x16;
typedef __attribute__((ext_vector_type(8)))  short short8;

static __device__ __forceinline__ ushort f2bf(float f) {
    uint32_t u = __float_as_uint(f);
    uint32_t r = (u + 0x7fffu + ((u >> 16) & 1u)) >> 16;
    return (ushort)r;
}
static __device__ __forceinline__ float bf2f(ushort h) {
    return __uint_as_float(((uint32_t)h) << 16);
}

// Kernel 1: fp32 -> bf16 cast into ws, plus per-row sum of squares of the
// *bf16-rounded* values (so the distance diagonal cancels against MFMA's
// fp32-accumulated gram[s,s]).
__global__ void prep_kernel(const float* __restrict__ x,
                            ushort* __restrict__ xb,
                            float* __restrict__ sq) {
    const int row  = blockIdx.x * 4 + (threadIdx.x >> 6);   // one wave per row
    const int lane = threadIdx.x & 63;
    const float4 v = *reinterpret_cast<const float4*>(x + (size_t)row * EDIM + lane * 4);
    ushort4 h;
    h.x = f2bf(v.x); h.y = f2bf(v.y); h.z = f2bf(v.z); h.w = f2bf(v.w);
    *reinterpret_cast<ushort4*>(xb + (size_t)row * EDIM + lane * 4) = h;
    const float fx = bf2f(h.x), fy = bf2f(h.y), fz = bf2f(h.z), fw = bf2f(h.w);
    float s = fx * fx + fy * fy + fz * fz + fw * fw;
    #pragma unroll
    for (int m = 1; m < 64; m <<= 1) s += __shfl_xor(s, m);
    if (lane == 0) sq[row] = s;
}

// Kernel 2: fused gram-GEMM + softmax, one workgroup = 32 rows x 2048 cols.
// 8 waves; wave w owns column stripe [w*256, w*256+256). Accumulators hold the
// whole 32x2048 tile (128 f32 regs/lane); after exp, row sums are reduced via
// shfl butterfly (cols within wave) + LDS (across waves); then scaled + stored.
__global__ __launch_bounds__(512, 2) void sims_main(
        const ushort* __restrict__ xb,
        const float*  __restrict__ sq,
        float* __restrict__ out) {
    const int b      = blockIdx.y;
    const int rowblk = blockIdx.x;            // 0..63
    const int tid    = threadIdx.x;
    const int wave   = tid >> 6;              // 0..7
    const int lane   = tid & 63;
    const int l31    = lane & 31;
    const int hi     = lane >> 5;             // 0/1

    const int row_base = rowblk * 32;
    const int col_base = wave * 256;

    const ushort* xbB = xb + (size_t)b * SEQ * EDIM;
    // A frag: row = row_base + l31, k-chunk = hi*8 + i  (8 contiguous bf16 = 16B)
    const ushort* aptr = xbB + (size_t)(row_base + l31) * EDIM + hi * 8;
    // B frag (B^T layout, x[t,e]): col t = col_base + cb*32 + l31
    const ushort* bptr = xbB + (size_t)(col_base + l31) * EDIM + hi * 8;

    f32x16 acc[8];
    #pragma unroll
    for (int cb = 0; cb < 8; ++cb) acc[cb] = (f32x16)0.0f;

    #pragma unroll 2
    for (int ks = 0; ks < 16; ++ks) {          // K = 256 = 16 steps of 16
        const int eo = ks * 16;
        const short8 a = *reinterpret_cast<const short8*>(aptr + eo);
        #pragma unroll
        for (int cb = 0; cb < 8; ++cb) {
            const short8 bb = *reinterpret_cast<const short8*>(bptr + cb * (32 * EDIM) + eo);
            acc[cb] = __builtin_amdgcn_mfma_f32_32x32x16_bf16(a, bb, acc[cb], 0, 0, 0);
        }
    }

    // --- epilogue: exp(-dist/T) in-place, then row sums ---
    constexpr float kC = (float)(-1.4426950408889634 / 13.544);  // -log2(e)/T
    const float* sqB = sq + b * SEQ;
    float sqc[8];
    #pragma unroll
    for (int cb = 0; cb < 8; ++cb) sqc[cb] = sqB[col_base + cb * 32 + l31];
    float sqr[16];
    #pragma unroll
    for (int r = 0; r < 16; ++r) sqr[r] = sqB[row_base + (r & 3) + 8 * (r >> 2) + 4 * hi];

    float part[16];
    #pragma unroll
    for (int r = 0; r < 16; ++r) {
        float p = 0.0f;
        #pragma unroll
        for (int cb = 0; cb < 8; ++cb) {
            const float d = sqr[r] + sqc[cb] - 2.0f * acc[cb][r];
            const float e = exp2f(d * kC);
            acc[cb][r] = e;
            p += e;
        }
        part[r] = p;
    }
    // butterfly sum over the 32 columns within each half-wave
    #pragma unroll
    for (int r = 0; r < 16; ++r) {
        float p = part[r];
        p += __shfl_xor(p, 1);
        p += __shfl_xor(p, 2);
        p += __shfl_xor(p, 4);
        p += __shfl_xor(p, 8);
        p += __shfl_xor(p, 16);
        part[r] = p;
    }

    __shared__ float red[32][9];   // [row][wave], padded
    __shared__ float inv[32];
    if (l31 == 0) {                // lanes 0 and 32 of each wave
        #pragma unroll
        for (int r = 0; r < 16; ++r) {
            const int lrow = (r & 3) + 8 * (r >> 2) + 4 * hi;
            red[lrow][wave] = part[r];
        }
    }
    __syncthreads();
    if (tid < 32) {
        float s = 0.0f;
        #pragma unroll
        for (int w = 0; w < 8; ++w) s += red[tid][w];
        inv[tid] = 1.0f / s;
    }
    __syncthreads();

    float invr[16];
    #pragma unroll
    for (int r = 0; r < 16; ++r) invr[r] = inv[(r & 3) + 8 * (r >> 2) + 4 * hi];

    float* outB = out + (size_t)b * SEQ * SEQ;
    #pragma unroll
    for (int r = 0; r < 16; ++r) {
        const int lrow = (r & 3) + 8 * (r >> 2) + 4 * hi;
        float* orow = outB + (size_t)(row_base + lrow) * SEQ + col_base + l31;
        const float scale = invr[r];
        #pragma unroll
        for (int cb = 0; cb < 8; ++cb) {
            orow[cb * 32] = acc[cb][r] * scale;
        }
    }
}

extern "C" void kernel_launch(void* const* d_in, const int* in_sizes, int n_in,
                              void* d_out, int out_size, void* d_ws, size_t ws_size,
                              hipStream_t stream) {
    (void)in_sizes; (void)n_in; (void)out_size; (void)ws_size;
    const float* x = (const float*)d_in[0];
    float* out = (float*)d_out;

    ushort* xb = (ushort*)d_ws;                                   // 16 MB bf16 copy of x
    float*  sq = (float*)((char*)d_ws + (size_t)NB * SEQ * EDIM * 2); // 128 KB row norms

    prep_kernel<<<NB * SEQ / 4, 256, 0, stream>>>(x, xb, sq);

    dim3 grid(SEQ / 32, NB);
    sims_main<<<grid, 512, 0, stream>>>(xb, sq, out);
}

// Round 2
// 151.008 us; speedup vs baseline: 1.3289x; 1.3289x over previous
//
#include <hip/hip_runtime.h>
#include <hip/hip_bf16.h>

#define NB 16
#define SEQ 2048
#define EDIM 256

typedef __attribute__((ext_vector_type(16))) float f32x16;
typedef __attribute__((ext_vector_type(8)))  short short8;

static __device__ __forceinline__ ushort f2bf(float f) {
    uint32_t u = __float_as_uint(f);
    uint32_t r = (u + 0x7fffu + ((u >> 16) & 1u)) >> 16;
    return (ushort)r;
}
static __device__ __forceinline__ float bf2f(ushort h) {
    return __uint_as_float(((uint32_t)h) << 16);
}

// async global->LDS, 16 bytes per lane. LDS dest must be wave-uniform base
// (HW adds lane*16); global src is per-lane.
static __device__ __forceinline__ void gll16(const ushort* g, ushort* l) {
    __builtin_amdgcn_global_load_lds(
        (const __attribute__((address_space(1))) uint32_t*)g,
        (__attribute__((address_space(3))) uint32_t*)l,
        16, 0, 0);
}

// Kernel 1: fp32 -> bf16, written in K-MAJOR PANEL layout:
//   xb[b][ks][t][j], ks = e>>4, j = e&15   (16 bf16 = 32 B per (ks,t))
// so each k-step's 64 KB B-tile is contiguous. Also per-row sum of squares of
// the bf16-rounded values (diagonal of dist cancels exactly vs MFMA gram).
__global__ void prep_kernel(const float* __restrict__ x,
                            ushort* __restrict__ xb,
                            float* __restrict__ sq) {
    __shared__ ushort sh[4][256];
    const int tid  = threadIdx.x;
    const int r    = tid >> 6;
    const int lane = tid & 63;
    const int grow = blockIdx.x * 4;
    const int row  = grow + r;

    const float4 v = *reinterpret_cast<const float4*>(x + (size_t)row * EDIM + lane * 4);
    ushort4 h;
    h.x = f2bf(v.x); h.y = f2bf(v.y); h.z = f2bf(v.z); h.w = f2bf(v.w);
    *reinterpret_cast<ushort4*>(&sh[r][lane * 4]) = h;

    const float fx = bf2f(h.x), fy = bf2f(h.y), fz = bf2f(h.z), fw = bf2f(h.w);
    float s = fx * fx + fy * fy + fz * fz + fw * fw;
    #pragma unroll
    for (int m = 1; m < 64; m <<= 1) s += __shfl_xor(s, m);
    if (lane == 0) sq[row] = s;

    __syncthreads();

    // transpose out: 16 threads per ks write 128 B contiguous
    const int b   = grow >> 11;
    const int t0  = grow & 2047;
    const int ksx = tid >> 4;           // 0..15
    const int idx = tid & 15;
    const int r2  = idx >> 2;
    const int j   = (idx & 3) * 4;
    ushort4 o = *reinterpret_cast<ushort4*>(&sh[r2][ksx * 16 + j]);
    *reinterpret_cast<ushort4*>(xb + (size_t)b * SEQ * EDIM
                                   + (size_t)ksx * SEQ * 16
                                   + (size_t)(t0 + r2) * 16 + j) = o;
}

// Kernel 2: fused gram-GEMM + one-pass softmax. WG = 32 rows x 2048 cols,
// 8 waves, wave w owns col stripe [w*256, w*256+256). Double-buffered LDS B
// (2x64KB) staged via global_load_lds; A panel (16KB) staged once.
__global__ __launch_bounds__(512, 1) void sims_main(
        const ushort* __restrict__ xb,
        const float*  __restrict__ sq,
        float* __restrict__ out) {
    __shared__ __align__(16) ushort Ab[8192];        // 16 KB: [ks][row][16]
    __shared__ __align__(16) ushort Bb[2][32768];    // 2 x 64 KB: [col][16]
    __shared__ float red[32][9];
    __shared__ float inv[32];

    const int b      = blockIdx.y;
    const int rowblk = blockIdx.x;
    const int tid    = threadIdx.x;
    const int wave   = tid >> 6;
    const int lane   = tid & 63;
    const int l31    = lane & 31;
    const int hi     = lane >> 5;

    const int row_base = rowblk * 32;

    const ushort* xbB = xb + (size_t)b * SEQ * EDIM;

    // ---- prologue: stage A panel (16 KB, 2 issues) + B tile ks=0 (8 issues)
    #pragma unroll
    for (int i = 0; i < 2; ++i) {
        const int ksa = i * 8 + wave;                       // wave-uniform
        gll16(xbB + (size_t)ksa * (SEQ * 16) + row_base * 16 + lane * 8,
              Ab + (i * 512 + wave * 64) * 8);
    }
    #pragma unroll
    for (int i = 0; i < 8; ++i) {
        gll16(xbB + (i * 512 + tid) * 8,
              &Bb[0][(i * 512 + (tid & ~63)) * 8]);
    }
    asm volatile("s_waitcnt vmcnt(0)" ::: "memory");
    __builtin_amdgcn_s_barrier();
    __builtin_amdgcn_sched_barrier(0);

    f32x16 acc[8];
    #pragma unroll
    for (int cb = 0; cb < 8; ++cb) acc[cb] = (f32x16)0.0f;

    const ushort* curb = &Bb[0][0];
    ushort*       nxtb = &Bb[1][0];

    #pragma unroll 1
    for (int ks = 0; ks < 16; ++ks) {
        // stage next tile (fire-and-forget, overlaps with compute below)
        if (ks < 15) {
            const ushort* gsrc = xbB + (size_t)(ks + 1) * (SEQ * 16);
            #pragma unroll
            for (int i = 0; i < 8; ++i) {
                gll16(gsrc + (i * 512 + tid) * 8,
                      nxtb + (i * 512 + (tid & ~63)) * 8);
            }
        }
        // compute current tile from LDS
        const short8 a = *reinterpret_cast<const short8*>(
            Ab + (ks * 64 + l31 * 2 + hi) * 8);
        const ushort* bbp = curb + (wave * 512 + l31 * 2 + hi) * 8;
        #pragma unroll
        for (int cb = 0; cb < 8; ++cb) {
            const short8 bv = *reinterpret_cast<const short8*>(bbp + cb * 512);
            acc[cb] = __builtin_amdgcn_mfma_f32_32x32x16_bf16(a, bv, acc[cb], 0, 0, 0);
        }
        __builtin_amdgcn_sched_barrier(0);
        if (ks < 15) { asm volatile("s_waitcnt vmcnt(0)" ::: "memory"); }
        __builtin_amdgcn_s_barrier();
        __builtin_amdgcn_sched_barrier(0);
        ushort* t = (ushort*)curb; curb = nxtb; nxtb = t;
    }

    // ---- epilogue: exp(-dist/T), row sums, scale, store (verified in R0) ----
    constexpr float kC = (float)(-1.4426950408889634 / 13.544);  // -log2(e)/T
    const int col_base = wave * 256;
    const float* sqB = sq + b * SEQ;
    float sqc[8];
    #pragma unroll
    for (int cb = 0; cb < 8; ++cb) sqc[cb] = sqB[col_base + cb * 32 + l31];
    float sqr[16];
    #pragma unroll
    for (int r = 0; r < 16; ++r) sqr[r] = sqB[row_base + (r & 3) + 8 * (r >> 2) + 4 * hi];

    float part[16];
    #pragma unroll
    for (int r = 0; r < 16; ++r) {
        float p = 0.0f;
        #pragma unroll
        for (int cb = 0; cb < 8; ++cb) {
            const float d = sqr[r] + sqc[cb] - 2.0f * acc[cb][r];
            const float e = exp2f(d * kC);
            acc[cb][r] = e;
            p += e;
        }
        part[r] = p;
    }
    #pragma unroll
    for (int r = 0; r < 16; ++r) {
        float p = part[r];
        p += __shfl_xor(p, 1);
        p += __shfl_xor(p, 2);
        p += __shfl_xor(p, 4);
        p += __shfl_xor(p, 8);
        p += __shfl_xor(p, 16);
        part[r] = p;
    }

    if (l31 == 0) {
        #pragma unroll
        for (int r = 0; r < 16; ++r) {
            const int lrow = (r & 3) + 8 * (r >> 2) + 4 * hi;
            red[lrow][wave] = part[r];
        }
    }
    __syncthreads();
    if (tid < 32) {
        float s = 0.0f;
        #pragma unroll
        for (int w = 0; w < 8; ++w) s += red[tid][w];
        inv[tid] = 1.0f / s;
    }
    __syncthreads();

    float invr[16];
    #pragma unroll
    for (int r = 0; r < 16; ++r) invr[r] = inv[(r & 3) + 8 * (r >> 2) + 4 * hi];

    float* outB = out + (size_t)b * SEQ * SEQ;
    #pragma unroll
    for (int r = 0; r < 16; ++r) {
        const int lrow = (r & 3) + 8 * (r >> 2) + 4 * hi;
        float* orow = outB + (size_t)(row_base + lrow) * SEQ + col_base + l31;
        const float scale = invr[r];
        #pragma unroll
        for (int cb = 0; cb < 8; ++cb) {
            orow[cb * 32] = acc[cb][r] * scale;
        }
    }
}

extern "C" void kernel_launch(void* const* d_in, const int* in_sizes, int n_in,
                              void* d_out, int out_size, void* d_ws, size_t ws_size,
                              hipStream_t stream) {
    (void)in_sizes; (void)n_in; (void)out_size; (void)ws_size;
    const float* x = (const float*)d_in[0];
    float* out = (float*)d_out;

    ushort* xb = (ushort*)d_ws;                                      // 16 MB bf16, k-major panels
    float*  sq = (float*)((char*)d_ws + (size_t)NB * SEQ * EDIM * 2); // 128 KB row norms

    prep_kernel<<<NB * SEQ / 4, 256, 0, stream>>>(x, xb, sq);

    dim3 grid(SEQ / 32, NB);
    sims_main<<<grid, 512, 0, stream>>>(xb, sq, out);
}

// Round 3
// 124.419 us; speedup vs baseline: 1.6129x; 1.2137x over previous
//
#include <hip/hip_runtime.h>
#include <hip/hip_bf16.h>

#define NB 16
#define SEQ 2048
#define EDIM 256

typedef __attribute__((ext_vector_type(16))) float f32x16;
typedef __attribute__((ext_vector_type(8)))  short short8;

static __device__ __forceinline__ ushort f2bf(float f) {
    uint32_t u = __float_as_uint(f);
    uint32_t r = (u + 0x7fffu + ((u >> 16) & 1u)) >> 16;
    return (ushort)r;
}
static __device__ __forceinline__ float bf2f(ushort h) {
    return __uint_as_float(((uint32_t)h) << 16);
}

// async global->LDS, 16 bytes per lane. LDS dest is wave-uniform base
// (HW adds lane*16); global src is per-lane (enables source-side swizzle).
static __device__ __forceinline__ void gll16(const ushort* g, ushort* l) {
    __builtin_amdgcn_global_load_lds(
        (const __attribute__((address_space(1))) uint32_t*)g,
        (__attribute__((address_space(3))) uint32_t*)l,
        16, 0, 0);
}

// Kernel 1: fp32 -> bf16 in K-MAJOR PANEL layout xb[b][ks][t][j] (ks=e>>4,
// j=e&15), plus per-row sum of squares of the bf16-rounded values (distance
// diagonal then cancels exactly against the fp32-accumulated MFMA gram).
__global__ void prep_kernel(const float* __restrict__ x,
                            ushort* __restrict__ xb,
                            float* __restrict__ sq) {
    __shared__ ushort sh[4][256];
    const int tid  = threadIdx.x;
    const int r    = tid >> 6;
    const int lane = tid & 63;
    const int grow = blockIdx.x * 4;
    const int row  = grow + r;

    const float4 v = *reinterpret_cast<const float4*>(x + (size_t)row * EDIM + lane * 4);
    ushort4 h;
    h.x = f2bf(v.x); h.y = f2bf(v.y); h.z = f2bf(v.z); h.w = f2bf(v.w);
    *reinterpret_cast<ushort4*>(&sh[r][lane * 4]) = h;

    const float fx = bf2f(h.x), fy = bf2f(h.y), fz = bf2f(h.z), fw = bf2f(h.w);
    float s = fx * fx + fy * fy + fz * fz + fw * fw;
    #pragma unroll
    for (int m = 1; m < 64; m <<= 1) s += __shfl_xor(s, m);
    if (lane == 0) sq[row] = s;

    __syncthreads();

    const int b   = grow >> 11;
    const int t0  = grow & 2047;
    const int ksx = tid >> 4;           // 0..15
    const int idx = tid & 15;
    const int r2  = idx >> 2;
    const int j   = (idx & 3) * 4;
    ushort4 o = *reinterpret_cast<ushort4*>(&sh[r2][ksx * 16 + j]);
    *reinterpret_cast<ushort4*>(xb + (size_t)b * SEQ * EDIM
                                   + (size_t)ksx * SEQ * 16
                                   + (size_t)(t0 + r2) * 16 + j) = o;
}

// Kernel 2: fused gram-GEMM + one-pass softmax. WG = 32 rows x 2048 cols,
// 8 waves; wave w owns cols [w*256,(w+1)*256). B staging is WAVE-PRIVATE
// (2 x 8KB per wave, double-buffered) -> no barriers in the K-loop; each
// wave self-paces on counted vmcnt. Chunk swizzle p(n)=n^((n>>3)&7) applied
// at the global SOURCE (per-lane) and on the ds_read position (involution)
// makes every 8-lane read group hit all 32 banks.
__global__ __launch_bounds__(512, 2) void sims_main(
        const ushort* __restrict__ xb,
        const float*  __restrict__ sq,
        float* __restrict__ out) {
    __shared__ __align__(16) ushort Ab[16 * 512];        // 16 KB: [ks][64 chunks][8]
    __shared__ __align__(16) ushort Bb[2][8][512 * 8];   // 2 x 8 waves x 8 KB
    __shared__ float red[32][9];
    __shared__ float inv[32];

    const int b      = blockIdx.y;
    const int rowblk = blockIdx.x;
    const int tid    = threadIdx.x;
    const int wave   = tid >> 6;
    const int lane   = tid & 63;
    const int l31    = lane & 31;
    const int hi     = lane >> 5;

    const int row_base = rowblk * 32;
    const ushort* xbB = xb + (size_t)b * SEQ * EDIM;

    // ---- A panel (shared): wave w stages ks = 2w, 2w+1; one barrier total.
    {
        const int gl   = lane ^ ((lane >> 3) & 7);   // src chunk (involution)
        const int r    = gl >> 1;
        const int half = gl & 1;
        #pragma unroll
        for (int i = 0; i < 2; ++i) {
            const int ksa = wave * 2 + i;
            gll16(xbB + (size_t)ksa * (SEQ * 16) + (row_base + r) * 16 + half * 8,
                  Ab + ksa * 512);
        }
    }
    asm volatile("s_waitcnt vmcnt(0)" ::: "memory");
    __builtin_amdgcn_s_barrier();
    __builtin_amdgcn_sched_barrier(0);

    // ---- wave-private B staging ----
    const int glane = lane ^ ((lane >> 3) & 7);
    #define STAGE_B(dbuf, kstep)                                                  \
        {                                                                         \
            const ushort* gsrc_ = xbB + (size_t)(kstep) * (SEQ * 16);             \
            ushort* ldst_ = &Bb[(dbuf)][wave][0];                                 \
            _Pragma("unroll")                                                     \
            for (int i_ = 0; i_ < 8; ++i_) {                                      \
                const int g_ = i_ * 64 + glane;                                   \
                gll16(gsrc_ + (wave * 256 + (g_ >> 1)) * 16 + (g_ & 1) * 8,       \
                      ldst_ + i_ * 512);                                          \
            }                                                                     \
        }

    STAGE_B(0, 0);
    STAGE_B(1, 1);

    f32x16 acc[8];
    #pragma unroll
    for (int cb = 0; cb < 8; ++cb) acc[cb] = (f32x16)0.0f;

    const int r6  = l31 * 2 + hi;
    const int pr6 = r6 ^ ((r6 >> 3) & 7);            // swizzled read position

    #pragma unroll 1
    for (int ks = 0; ks < 16; ++ks) {
        if (ks < 15) { asm volatile("s_waitcnt vmcnt(8)" ::: "memory"); }
        else         { asm volatile("s_waitcnt vmcnt(0)" ::: "memory"); }
        __builtin_amdgcn_sched_barrier(0);

        const short8 a = *reinterpret_cast<const short8*>(Ab + ks * 512 + pr6 * 8);
        short8 bv[8];
        const ushort* breg = &Bb[ks & 1][wave][0];
        #pragma unroll
        for (int cb = 0; cb < 8; ++cb)
            bv[cb] = *reinterpret_cast<const short8*>(breg + (cb * 64 + pr6) * 8);

        __builtin_amdgcn_sched_barrier(0);
        asm volatile("s_waitcnt lgkmcnt(0)" ::: "memory");
        __builtin_amdgcn_sched_barrier(0);

        if (ks < 14) STAGE_B(ks & 1, ks + 2);        // safe: reads are done

        #pragma unroll
        for (int cb = 0; cb < 8; ++cb)
            acc[cb] = __builtin_amdgcn_mfma_f32_32x32x16_bf16(a, bv[cb], acc[cb], 0, 0, 0);
    }

    // ---- epilogue: exp(-dist/T), row sums, scale, store (verified R0/R1) ----
    constexpr float kC = (float)(-1.4426950408889634 / 13.544);  // -log2(e)/T
    const int col_base = wave * 256;
    const float* sqB = sq + b * SEQ;
    float sqc[8];
    #pragma unroll
    for (int cb = 0; cb < 8; ++cb) sqc[cb] = sqB[col_base + cb * 32 + l31];
    float sqr[16];
    #pragma unroll
    for (int r = 0; r < 16; ++r) sqr[r] = sqB[row_base + (r & 3) + 8 * (r >> 2) + 4 * hi];

    float part[16];
    #pragma unroll
    for (int r = 0; r < 16; ++r) {
        float p = 0.0f;
        #pragma unroll
        for (int cb = 0; cb < 8; ++cb) {
            const float d = sqr[r] + sqc[cb] - 2.0f * acc[cb][r];
            const float e = exp2f(d * kC);
            acc[cb][r] = e;
            p += e;
        }
        part[r] = p;
    }
    #pragma unroll
    for (int r = 0; r < 16; ++r) {
        float p = part[r];
        p += __shfl_xor(p, 1);
        p += __shfl_xor(p, 2);
        p += __shfl_xor(p, 4);
        p += __shfl_xor(p, 8);
        p += __shfl_xor(p, 16);
        part[r] = p;
    }

    if (l31 == 0) {
        #pragma unroll
        for (int r = 0; r < 16; ++r) {
            const int lrow = (r & 3) + 8 * (r >> 2) + 4 * hi;
            red[lrow][wave] = part[r];
        }
    }
    __syncthreads();
    if (tid < 32) {
        float s = 0.0f;
        #pragma unroll
        for (int w = 0; w < 8; ++w) s += red[tid][w];
        inv[tid] = 1.0f / s;
    }
    __syncthreads();

    float invr[16];
    #pragma unroll
    for (int r = 0; r < 16; ++r) invr[r] = inv[(r & 3) + 8 * (r >> 2) + 4 * hi];

    float* outB = out + (size_t)b * SEQ * SEQ;
    #pragma unroll
    for (int r = 0; r < 16; ++r) {
        const int lrow = (r & 3) + 8 * (r >> 2) + 4 * hi;
        float* orow = outB + (size_t)(row_base + lrow) * SEQ + col_base + l31;
        const float scale = invr[r];
        #pragma unroll
        for (int cb = 0; cb < 8; ++cb) {
            orow[cb * 32] = acc[cb][r] * scale;
        }
    }
}

extern "C" void kernel_launch(void* const* d_in, const int* in_sizes, int n_in,
                              void* d_out, int out_size, void* d_ws, size_t ws_size,
                              hipStream_t stream) {
    (void)in_sizes; (void)n_in; (void)out_size; (void)ws_size;
    const float* x = (const float*)d_in[0];
    float* out = (float*)d_out;

    ushort* xb = (ushort*)d_ws;                                       // 16 MB bf16, k-major panels
    float*  sq = (float*)((char*)d_ws + (size_t)NB * SEQ * EDIM * 2); // 128 KB row norms

    prep_kernel<<<NB * SEQ / 4, 256, 0, stream>>>(x, xb, sq);

    dim3 grid(SEQ / 32, NB);
    sims_main<<<grid, 512, 0, stream>>>(xb, sq, out);
}